// Round 8
// baseline (1900.202 us; speedup 1.0000x reference)
//
#include <hip/hip_runtime.h>
#include <hip/hip_bf16.h>

#define B_ 32
#define S_ 512
#define IN_ 300
#define H_ 180
#define G4_ 720
#define OUT_ 60
#define R_ 16384
#define TC_ 32
#define NC_ 16
#define NPK_ 92

// packed-weight region word offsets (wfu = uint/float view of same region)
// Whh rows are u-major permuted: packed col t holds row (t&3)*180 + (t>>2).
#define PWHH_O  0u        // uints [4][92][720] f16-pair Whh = 264,960
#define PW0_O   264960u   // uints [720][150] f16-pair Wih0 = 108,000
#define PWR_O   372960u   // uints [3][720][90] f16-pair WihR = 194,400
#define BIASF_O 567360u   // fp32 [4][720] (bih+bhh), gate-major = 2,880
#define LINWF_O 570240u   // fp32 [60][180] = 10,800
#define LINBF_O 581040u   // fp32 [60]
#define WFT_    581100u

// ws float offsets (r0-proven map; total 9,105,901 fl = 36.4 MB)
#define XG_O   0u         // [4 layers][2 ring][1024][720] fp32 = 5,898,240
#define HR_O   5898240u   // [3 layers][2 ring][1024][180] fp32 = 1,105,920
#define H3_O   7004160u   // bf16 [16384][180] = 1,474,560 fl
#define WFU_O  8478720u   // 581,100 fl
#define STH_O  9059820u   // [4][32][180] h state
#define STC_O  9082860u   // [4][32][180] c state
#define FLAG_O 9105900u
#define XGSLOT 737280
#define HRSLOT 184320

// LDS overlay (words): [0,37440) = 13 groups x [720 cols x 4 words] Whh
// k-pairs 40..91; [37440,37808) = hpk [2 batch][2 buf][92]. GEMM overlays
// Asu at [0,2040), Bsu at [2040,4080). Total 151,232 B (<= 160 KiB).
#define WLDS_W 37440
#define HP0_   37440
#define SHB_W  37808

#if defined(__has_builtin)
#if __has_builtin(__builtin_amdgcn_fdot2)
#define HAVE_FDOT2 1
#endif
#if __has_builtin(__builtin_amdgcn_mov_dpp)
#define HAVE_DPP 1
#endif
#endif

typedef _Float16 f16x2 __attribute__((ext_vector_type(2)));

struct Plan {
  int nl; int ll[4]; int lc[4];
  int ng; int gl[4]; int gc[4];
};

__device__ __forceinline__ float sigf(float x)   { return 1.f / (1.f + __expf(-x)); }
__device__ __forceinline__ float tanhf2(float x) { return 2.f / (1.f + __expf(-2.f * x)) - 1.f; }
__device__ __forceinline__ float toF(__hip_bfloat16 x) { return __bfloat162float(x); }
__device__ __forceinline__ float ldr(const void* p, long i, int fl) {
  return fl ? ((const float*)p)[i] : toF(((const __hip_bfloat16*)p)[i]);
}
__device__ __forceinline__ unsigned f16b(_Float16 h) {
  union { _Float16 f; unsigned short s; } x; x.f = h; return x.s;
}
__device__ __forceinline__ float h2f(unsigned s) {
  union { unsigned short s; _Float16 f; } x; x.s = (unsigned short)(s & 0xFFFFu);
  return (float)x.f;
}
__device__ __forceinline__ f16x2 u2h(unsigned u) {
  union { unsigned u; f16x2 v; } x; x.u = u; return x.v;
}
__device__ __forceinline__ float fd2(unsigned hu, unsigned wu, float acc) {
#ifdef HAVE_FDOT2
  return __builtin_amdgcn_fdot2(u2h(hu), u2h(wu), acc, false);
#else
  return acc + h2f(hu) * h2f(wu) + h2f(hu >> 16) * h2f(wu >> 16);
#endif
}
__device__ __forceinline__ unsigned packpair_f32(float lo, float hi) {
  return f16b((_Float16)lo) | (f16b((_Float16)hi) << 16);
}
__device__ __forceinline__ unsigned packpair_bf16(unsigned u) {
  union { unsigned v; float f; } a, b;
  a.v = u << 16; b.v = u & 0xFFFF0000u;
  return packpair_f32(a.f, b.f);
}

// quad broadcast: every lane gets quad-lane J's value (VALU DPP, no LDS)
#ifdef HAVE_DPP
#define QBC(dst, src, J) { \
  const int qv_ = __builtin_amdgcn_mov_dpp(__float_as_int(src), (J) * 85, 0xF, 0xF, false); \
  dst = __int_as_float(qv_); }
#else
#define QBC(dst, src, J) dst = __shfl(src, (((threadIdx.x & 63) & ~3) + (J)), 64);
#endif

// 10 register groups (k-pairs 0..39) + 13 LDS groups (k-pairs 40..91)
#define REP10(M) M(0) M(1) M(2) M(3) M(4) M(5) M(6) M(7) M(8) M(9)
#define REP13(M) M(0) M(1) M(2) M(3) M(4) M(5) M(6) M(7) M(8) M(9) M(10) M(11) M(12)
#define LW(n) \
  unsigned w##n##a = wp0[(4*n+0)*G4_], w##n##b = wp0[(4*n+1)*G4_], \
           w##n##c = wp0[(4*n+2)*G4_], w##n##d = wp0[(4*n+3)*G4_];
#define PW(n) \
  asm volatile("" : "+v"(w##n##a), "+v"(w##n##b), "+v"(w##n##c), "+v"(w##n##d));
// M=2: same weights serve both batches (8 fd2 per group)
#define ST2R(n) { \
  const uint4 hA_ = *(const uint4*)&hbA[4*(n)]; \
  const uint4 hB_ = *(const uint4*)&hbB[4*(n)]; \
  aA0 = fd2(hA_.x, w##n##a, aA0); aA1 = fd2(hA_.y, w##n##b, aA1); \
  aA2 = fd2(hA_.z, w##n##c, aA2); aA3 = fd2(hA_.w, w##n##d, aA3); \
  aB0 = fd2(hB_.x, w##n##a, aB0); aB1 = fd2(hB_.y, w##n##b, aB1); \
  aB2 = fd2(hB_.z, w##n##c, aB2); aB3 = fd2(hB_.w, w##n##d, aB3); }
#define ST2L(n) { \
  const uint4 hA_ = *(const uint4*)&hbA[40 + 4*(n)]; \
  const uint4 hB_ = *(const uint4*)&hbB[40 + 4*(n)]; \
  const uint4 wv_ = *(const uint4*)&wldp[(n) * 2880]; \
  aA0 = fd2(hA_.x, wv_.x, aA0); aA1 = fd2(hA_.y, wv_.y, aA1); \
  aA2 = fd2(hA_.z, wv_.z, aA2); aA3 = fd2(hA_.w, wv_.w, aA3); \
  aB0 = fd2(hB_.x, wv_.x, aB0); aB1 = fd2(hB_.y, wv_.y, aB1); \
  aB2 = fd2(hB_.z, wv_.z, aB2); aB3 = fd2(hB_.w, wv_.w, aB3); }

// ---------------------------------------------------------------------------
__global__ __launch_bounds__(256) void detect_kernel(
    const unsigned short* __restrict__ xw, int* __restrict__ flag) {
  __shared__ int cnt;
  if (threadIdx.x == 0) cnt = 0;
  __syncthreads();
  int lc = 0;
  for (int i = threadIdx.x; i < 2048; i += 256) {
    const int e = (xw[i] >> 7) & 0xFF;
    if (e >= 0xC0 || (e > 0 && e < 0x40)) lc++;
  }
  atomicAdd(&cnt, lc);
  __syncthreads();
  if (threadIdx.x == 0) *flag = (cnt > 100) ? 1 : 0;
}

// ---------------------------------------------------------------------------
// prep: Whh packed [l][jp][col] with u-major row permute; Wih0 [o][150];
// WihR [l][o][90]; bias/linw/linb fp32.
// ---------------------------------------------------------------------------
__global__ __launch_bounds__(256) void prep_kernel(
    const void* __restrict__ wih0, const void* __restrict__ wihr,
    const void* __restrict__ whh,  const void* __restrict__ bih,
    const void* __restrict__ bhh,  const void* __restrict__ linw,
    const void* __restrict__ linb, float* __restrict__ wf,
    const int* __restrict__ flag) {
  const unsigned i = blockIdx.x * 256u + threadIdx.x;
  if (i >= WFT_) return;
  const int fl = *flag;
  if (i < PW0_O) {            // Whh packed, row = (col&3)*180 + (col>>2)
    const unsigned l = i / 66240u, r = i % 66240u;
    const unsigned jp = r / 720u, o = r % 720u;
    const unsigned ro = (o & 3u) * 180u + (o >> 2);
    unsigned u = 0u;
    if (jp < 90u) {
      const long b = (long)l * 129600 + (long)ro * H_;
      u = packpair_f32(ldr(whh, b + 2 * jp, fl), ldr(whh, b + 2 * jp + 1, fl));
    }
    ((unsigned*)wf)[i] = u;
    return;
  }
  if (i < PWR_O) {            // Wih0 [o][150] pairs
    const unsigned j = i - PW0_O, o = j / 150u, kp = j % 150u;
    const long b = (long)o * IN_;
    ((unsigned*)wf)[i] =
        packpair_f32(ldr(wih0, b + 2 * kp, fl), ldr(wih0, b + 2 * kp + 1, fl));
    return;
  }
  if (i < BIASF_O) {          // WihR [l][o][90] pairs
    const unsigned j = i - PWR_O, l = j / 64800u, r = j % 64800u;
    const unsigned o = r / 90u, kp = r % 90u;
    const long b = (long)l * 129600 + (long)o * H_;
    ((unsigned*)wf)[i] =
        packpair_f32(ldr(wihr, b + 2 * kp, fl), ldr(wihr, b + 2 * kp + 1, fl));
    return;
  }
  float v;
  if (i < LINWF_O)      { const unsigned j = i - BIASF_O; v = ldr(bih, j, fl) + ldr(bhh, j, fl); }
  else if (i < LINBF_O) v = ldr(linw, i - LINWF_O, fl);
  else                  v = ldr(linb, i - LINBF_O, fl);
  wf[i] = v;
}

// ---------------------------------------------------------------------------
// fused: blocks [0, nl*16) = LSTM jobs (M=2 batches/block, u-major threads;
// Whh split: k-pairs 0..39 register-resident, 40..91 in LDS (149.8 KB,
// loaded once per block); DPP quad gather; one raw barrier per step).
// rest = barrier GEMM (r0 proven tiling, coalesced gate-major xg epilogue),
// overlaying its A/B staging in the same LDS buffer.
// ---------------------------------------------------------------------------
__global__ __launch_bounds__(768, 3) void fused_kernel(
    const void* __restrict__ x, const int* __restrict__ flag,
    const unsigned* __restrict__ wfu,
    float* __restrict__ xg, float* __restrict__ hr,
    __hip_bfloat16* __restrict__ h3,
    float* __restrict__ sth, float* __restrict__ stc, Plan p) {
  __shared__ __align__(16) unsigned shb[SHB_W];   // 151,232 B overlay

  const int bid = blockIdx.x;
  if (bid < p.nl * 16) {
    // ---------------- LSTM: M=2, u-major, LDS+reg split weights ----------
    const int j = bid >> 4, pb = bid & 15;
    const int l = p.ll[j], c = p.lc[j];
    const int b0 = pb * 2, b1 = b0 + 1;
    const int o = threadIdx.x;                    // 0..767
    const int oc = (o < G4_) ? o : (G4_ - 1);
    const int g = o & 3, u = o >> 2;              // unit 0..191 (pad >=180)
    const bool act = (o < G4_);
    const unsigned* wl0 = wfu + PWHH_O + (unsigned)l * (NPK_ * G4_);
    const unsigned* wp0 = wl0 + oc;
    REP10(LW)
    REP10(PW)
    // fill LDS weights: k-pairs 40..91, quad-interleaved [grp][col*4+j]
    for (int e = o; e < WLDS_W; e += 768) {
      const int jq = e / 720, oo = e - jq * 720;   // jq = jp-40 (0..51)
      shb[(jq >> 2) * 2880 + oo * 4 + (jq & 3)] = wl0[(40 + jq) * 720 + oo];
    }
    const float* xgs = xg + (long)(l * 2 + (c & 1)) * XGSLOT;
    float* hrs = hr + (long)((l < 3 ? l : 0) * 2 + (c & 1)) * HRSLOT;
    float cstA = 0.f, cstB = 0.f, hA0 = 0.f, hB0 = 0.f;
    if (c != 0 && act) {
      cstA = stc[(l * 32 + b0) * H_ + u]; hA0 = sth[(l * 32 + b0) * H_ + u];
      cstB = stc[(l * 32 + b1) * H_ + u]; hB0 = sth[(l * 32 + b1) * H_ + u];
    }
    // zero pad words (90,91) of all four hpk buffers
    if (o < 8) shb[HP0_ + (o >> 1) * 92 + 90 + (o & 1)] = 0u;
    // seed buf0 for both batches
    {
      const unsigned vA = f16b((_Float16)hA0);
      const unsigned nA = __shfl_down(vA, 4);
      const unsigned vB = f16b((_Float16)hB0);
      const unsigned nB = __shfl_down(vB, 4);
      if (act && (o & 7) == 0) {
        shb[HP0_ + (u >> 1)] = vA | (nA << 16);          // batch A buf0
        shb[HP0_ + 184 + (u >> 1)] = vB | (nB << 16);    // batch B buf0
      }
    }
    // gate-major xg: thread (u,g) reads column g*180+u (4x64B segs/wave)
    const int co = (oc & 3) * 180 + (oc >> 2);
    const float* xpA = xgs + (long)b0 * TC_ * G4_ + co;
    const float* xpB = xgs + (long)b1 * TC_ * G4_ + co;
    float xcA = xpA[0], xcB = xpB[0];
    const float sg = (g == 2) ? 2.f : 1.f;        // g-gate uses tanh
    __syncthreads();
    for (int tl = 0; tl < TC_; ++tl) {
      const unsigned* hbA = shb + HP0_ + (tl & 1) * 92;
      const unsigned* hbB = shb + HP0_ + 184 + (tl & 1) * 92;
      const unsigned* wldp = shb + oc * 4;
      float aA0 = xcA, aA1 = 0.f, aA2 = 0.f, aA3 = 0.f;
      float aB0 = xcB, aB1 = 0.f, aB2 = 0.f, aB3 = 0.f;
      REP10(ST2R)
      REP13(ST2L)
      const float accA = (aA0 + aA1) + (aA2 + aA3);
      const float accB = (aB0 + aB1) + (aB2 + aB3);
      const int tn = (tl + 1 < TC_) ? tl + 1 : tl;
      xcA = xpA[(long)tn * G4_]; xcB = xpB[(long)tn * G4_];
      // unified activation: fma(s, 1/(1+exp(-s*x)) - 1, 1) = sig (s=1) / tanh (s=2)
      const float vA_ = 1.f / (1.f + __expf(-sg * accA));
      const float gvA = fmaf(sg, vA_ - 1.f, 1.f);
      const float vB_ = 1.f / (1.f + __expf(-sg * accB));
      const float gvB = fmaf(sg, vB_ - 1.f, 1.f);
      // quad gather: gates i,f,g,o live on quad lanes 0..3
      float qiA, qfA, qgA, qoA, qiB, qfB, qgB, qoB;
      QBC(qiA, gvA, 0) QBC(qfA, gvA, 1) QBC(qgA, gvA, 2) QBC(qoA, gvA, 3)
      QBC(qiB, gvB, 0) QBC(qfB, gvB, 1) QBC(qgB, gvB, 2) QBC(qoB, gvB, 3)
      cstA = qfA * cstA + qiA * qgA;
      cstB = qfB * cstB + qiB * qgB;
      const float hA = qoA * tanhf2(cstA);
      const float hB = qoB * tanhf2(cstB);
      const unsigned vA = f16b((_Float16)hA);
      const unsigned nA = __shfl_down(vA, 4);
      const unsigned vB = f16b((_Float16)hB);
      const unsigned nB = __shfl_down(vB, 4);
      const int wb = (tl & 1) ^ 1;
      if (act && (o & 7) == 0) {
        shb[HP0_ + wb * 92 + (u >> 1)] = vA | (nA << 16);
        shb[HP0_ + 184 + wb * 92 + (u >> 1)] = vB | (nB << 16);
      }
      if (act && g == 0) {
        if (l < 3) {
          hrs[(b0 * TC_ + tl) * H_ + u] = hA;
          hrs[(b1 * TC_ + tl) * H_ + u] = hB;
        } else {
          h3[((long)b0 * S_ + c * TC_ + tl) * H_ + u] = __float2bfloat16(hA);
          h3[((long)b1 * S_ + c * TC_ + tl) * H_ + u] = __float2bfloat16(hB);
        }
        if (tl == TC_ - 1) {
          sth[(l * 32 + b0) * H_ + u] = hA; stc[(l * 32 + b0) * H_ + u] = cstA;
          sth[(l * 32 + b1) * H_ + u] = hB; stc[(l * 32 + b1) * H_ + u] = cstB;
        }
      }
      // single raw barrier: hpk writes visible; stores/prefetch stay in flight
      asm volatile("s_waitcnt lgkmcnt(0)\n\ts_barrier" ::: "memory");
    }
    return;
  }

  // ---------------- GEMM: f16-pair dot2, r0 tiling, LDS overlay ----------
  const int gb = bid - p.nl * 16;
  const int g = threadIdx.x >> 8, t = threadIdx.x & 255;
  const int ti = gb * 3 + g;              // grid sized exactly: ti < ng*192
  const int jj = ti / 192, idx = ti % 192;
  const int rt = idx & 15, ct = idx >> 4;
  const int l = p.gl[jj], c = p.gc[jj];
  const int fl = *flag;
  const int KP = (l == 0) ? 150 : 90;     // k-pairs
  const unsigned* Wp = (l == 0) ? (wfu + PW0_O)
                                : (wfu + PWR_O + (unsigned)(l - 1) * 64800u);
  const float* bias = (const float*)wfu + BIASF_O + (unsigned)l * G4_;
  const float* hA = (l == 0) ? nullptr
                  : hr + (long)((l - 1) * 2 + (c & 1)) * HRSLOT;
  float* dst = xg + (long)(l * 2 + (c & 1)) * XGSLOT;
  const int rho0 = rt * 64, o0 = ct * 64;
  const int tx = t & 15, ty = t >> 4;
  float acc[4][4] = {};
  for (int kp0 = 0; kp0 < KP; kp0 += 10) {
    for (int e = t; e < 640; e += 256) {
      const int rl = e / 10, pp = e % 10;
      const int rho = rho0 + rl;
      unsigned av;
      if (l == 0) {
        const int bb = rho >> 5, tl = rho & 31;
        const long gr = (long)bb * S_ + c * TC_ + tl;
        if (fl == 0) av = packpair_bf16(((const unsigned*)x)[gr * 150 + kp0 + pp]);
        else { const float2 f = ((const float2*)x)[gr * 150 + kp0 + pp];
               av = packpair_f32(f.x, f.y); }
      } else {
        const float2 f = ((const float2*)hA)[(long)rho * 90 + kp0 + pp];
        av = packpair_f32(f.x, f.y);
      }
      shb[(g * 10 + pp) * 68 + rl] = av;                    // Asu
      const int o = o0 + rl;
      shb[2040 + (g * 10 + pp) * 68 + rl] =                 // Bsu
          (o < G4_) ? Wp[(long)o * KP + kp0 + pp] : 0u;
    }
    __syncthreads();
#pragma unroll
    for (int pp = 0; pp < 10; ++pp) {
      const uint4 a4 = *(const uint4*)&shb[(g * 10 + pp) * 68 + ty * 4];
      const uint4 b4 = *(const uint4*)&shb[2040 + (g * 10 + pp) * 68 + tx * 4];
      const unsigned av[4] = {a4.x, a4.y, a4.z, a4.w};
      const unsigned bv[4] = {b4.x, b4.y, b4.z, b4.w};
#pragma unroll
      for (int i = 0; i < 4; ++i)
#pragma unroll
        for (int j2 = 0; j2 < 4; ++j2) acc[i][j2] = fd2(av[i], bv[j2], acc[i][j2]);
    }
    __syncthreads();
  }
  // epilogue: coalesced gate-major write (r0 proven)
#pragma unroll
  for (int i = 0; i < 4; ++i) {
    const int rho = rho0 + ty * 4 + i;
#pragma unroll
    for (int j2 = 0; j2 < 4; ++j2) {
      const int o = o0 + tx * 4 + j2;
      if (o < G4_) dst[(long)rho * G4_ + o] = acc[i][j2] + bias[o];
    }
  }
}

// ---------------------------------------------------------------------------
// linear as tiled GEMM: [16384 x 180] @ [180 x 60] -> out[b][c][s].
// ---------------------------------------------------------------------------
__global__ __launch_bounds__(256) void linear_kernel(
    const __hip_bfloat16* __restrict__ h, const float* __restrict__ linw,
    const float* __restrict__ linb, float* __restrict__ out) {
  __shared__ __align__(16) float Ast[20][68];
  __shared__ __align__(16) float Bst[20][68];
  const int bt = blockIdx.x;
  const int b = bt >> 3, st0 = (bt & 7) * 64;
  const int t = threadIdx.x, tx = t & 15, ty = t >> 4;
  float acc[4][4] = {};
  for (int k0 = 0; k0 < H_; k0 += 20) {
    for (int e = t; e < 1280; e += 256) {
      const int rl = e / 20, kk = e % 20;
      Ast[kk][rl] = toF(h[(long)(b * S_ + st0 + rl) * H_ + k0 + kk]);
      Bst[kk][rl] = (rl < OUT_) ? linw[rl * H_ + k0 + kk] : 0.f;
    }
    __syncthreads();
#pragma unroll
    for (int kk = 0; kk < 20; ++kk) {
      const float4 a4 = *(const float4*)&Ast[kk][ty * 4];
      const float4 b4 = *(const float4*)&Bst[kk][tx * 4];
      const float av[4] = {a4.x, a4.y, a4.z, a4.w};
      const float bv[4] = {b4.x, b4.y, b4.z, b4.w};
#pragma unroll
      for (int i = 0; i < 4; ++i)
#pragma unroll
        for (int j2 = 0; j2 < 4; ++j2) acc[i][j2] += av[i] * bv[j2];
    }
    __syncthreads();
  }
#pragma unroll
  for (int i = 0; i < 4; ++i) {
    const int s = st0 + ty * 4 + i;
#pragma unroll
    for (int j2 = 0; j2 < 4; ++j2) {
      const int c = tx * 4 + j2;
      if (c < OUT_) out[((long)b * OUT_ + c) * S_ + s] = acc[i][j2] + linb[c];
    }
  }
}

// ---------------------------------------------------------------------------
__global__ __launch_bounds__(256) void mel_kernel(
    const float* __restrict__ in, float* __restrict__ out,
    const void* __restrict__ mw, const void* __restrict__ mb,
    int l, const int* __restrict__ flag) {
  const int fl = *flag;
  const int idx = blockIdx.x;
  const int s = (idx & 1) * 256 + threadIdx.x;
  const int c = (idx >> 1) % OUT_;
  const int b = idx / (2 * OUT_);
  const int j = c % 3, i = c / 3;
  float acc = ldr(mb, (l * 3 + j) * 20 + i, fl);
  const long wbase = (long)((l * 3 + j) * 20 + i) * 15;
#pragma unroll
  for (int q = 0; q < 3; ++q) {
    const int ch = 3 * i + q + j - 1;
    if (ch < 0 || ch >= OUT_) continue;
    const float* xr = in + ((long)b * OUT_ + ch) * S_;
#pragma unroll
    for (int k = 0; k < 5; ++k) {
      const int sp = s + k - 2;
      if (sp < 0 || sp >= S_) continue;
      acc += ldr(mw, wbase + q * 5 + k, fl) * xr[sp];
    }
  }
  out[((long)b * OUT_ + c) * S_ + s] = acc + in[((long)b * OUT_ + c) * S_ + s];
}

// ---------------------------------------------------------------------------
__global__ __launch_bounds__(256) void res_kernel(
    const float* __restrict__ lin, const float* __restrict__ mel,
    const void* __restrict__ rw, const void* __restrict__ rb,
    void* __restrict__ outp, const int* __restrict__ flag) {
  const int fl = *flag;
  const int q = threadIdx.x >> 6, lane = threadIdx.x & 63;
  const int bs = blockIdx.x * 4 + q;
  const int b = bs / S_, s = bs % S_;
  if (lane >= OUT_) return;
  const int c = lane;
  float acc = ldr(rb, c, fl);
  const float* x0 = lin + ((long)b * OUT_ + c) * S_;
  const float* x1 = mel + ((long)b * OUT_ + c) * S_;
#pragma unroll
  for (int k = 0; k < 5; ++k) {
    const int sp = s + k - 2;
    if (sp < 0 || sp >= S_) continue;
    acc += ldr(rw, c * 10 + k, fl) * x0[sp] + ldr(rw, c * 10 + 5 + k, fl) * x1[sp];
  }
  const long oi = (long)bs * OUT_ + c;
  if (fl == 0) ((__hip_bfloat16*)outp)[oi] = __float2bfloat16(acc);
  else ((float*)outp)[oi] = acc;
}

// ---------------------------------------------------------------------------
extern "C" void kernel_launch(void* const* d_in, const int* in_sizes, int n_in,
                              void* d_out, int out_size, void* d_ws, size_t ws_size,
                              hipStream_t stream) {
  const void* x    = d_in[0];
  const void* wih0 = d_in[1];
  const void* wihr = d_in[2];
  const void* whh  = d_in[3];
  const void* bih  = d_in[4];
  const void* bhh  = d_in[5];
  const void* linw = d_in[6];
  const void* linb = d_in[7];
  const void* melw = d_in[8];
  const void* melb = d_in[9];
  const void* resw = d_in[10];
  const void* resb = d_in[11];

  float* ws = (float*)d_ws;
  float* xg = ws + XG_O;
  float* hrp = ws + HR_O;
  __hip_bfloat16* h3 = (__hip_bfloat16*)(ws + H3_O);
  float* wf = ws + WFU_O;
  const unsigned* wfu = (const unsigned*)wf;
  float* sth = ws + STH_O;
  float* stc = ws + STC_O;
  int* flag = (int*)(ws + FLAG_O);
  float* lin = ws + XG_O;            // epilogue aliases dead xg region
  float* m1 = lin + 983040;
  float* m2 = m1 + 983040;

  detect_kernel<<<1, 256, 0, stream>>>((const unsigned short*)x, flag);
  prep_kernel<<<(WFT_ + 255) / 256, 256, 0, stream>>>(
      wih0, wihr, whh, bih, bhh, linw, linb, wf, flag);

  // prologue: gemm(0,0) only
  {
    Plan p = {};
    p.nl = 0; p.ng = 1; p.gl[0] = 0; p.gc[0] = 0;
    fused_kernel<<<64, 768, 0, stream>>>(x, flag, wfu, xg, hrp, h3, sth, stc, p);
  }
  // pipeline: lstm(l,c) at launch n = c + 2l; gemm(l,c) at n = c + 2l - 1
  for (int n = 0; n <= 21; ++n) {
    Plan p = {};
    for (int l = 0; l < 4; ++l) {
      const int c = n - 2 * l;
      if (c >= 0 && c < NC_) { p.ll[p.nl] = l; p.lc[p.nl] = c; p.nl++; }
    }
    for (int l = 0; l < 4; ++l) {
      const int c = n + 1 - 2 * l;
      if (c >= 0 && c < NC_) { p.gl[p.ng] = l; p.gc[p.ng] = c; p.ng++; }
    }
    const int grid = p.nl * 16 + p.ng * 64;
    fused_kernel<<<grid, 768, 0, stream>>>(x, flag, wfu, xg, hrp, h3, sth, stc, p);
  }

  linear_kernel<<<256, 256, 0, stream>>>(h3, wf + LINWF_O, wf + LINBF_O, lin);
  mel_kernel<<<B_ * OUT_ * 2, 256, 0, stream>>>(lin, m1, melw, melb, 0, flag);
  mel_kernel<<<B_ * OUT_ * 2, 256, 0, stream>>>(m1, m2, melw, melb, 1, flag);
  mel_kernel<<<B_ * OUT_ * 2, 256, 0, stream>>>(m2, m1, melw, melb, 2, flag);
  res_kernel<<<R_ / 4, 256, 0, stream>>>(lin, m1, resw, resb, d_out, flag);
}

// Round 9
// 1532.284 us; speedup vs baseline: 1.2401x; 1.2401x over previous
//
#include <hip/hip_runtime.h>
#include <hip/hip_bf16.h>

#define B_ 32
#define S_ 512
#define IN_ 300
#define H_ 180
#define G4_ 720
#define OUT_ 60
#define R_ 16384
#define TC_ 32
#define NC_ 16
#define NPK_ 92

// packed-weight region word offsets (wfu = uint/float view of same region)
#define PWHH_O  0u        // uints [4][92][720] f16-pair Whh^T = 264,960
#define PW0_O   264960u   // uints [720][150] f16-pair Wih0 = 108,000
#define PWR_O   372960u   // uints [3][720][90] f16-pair WihR = 194,400
#define BIASF_O 567360u   // fp32 [4][720] (bih+bhh) = 2,880
#define LINWF_O 570240u   // fp32 [60][180] = 10,800
#define LINBF_O 581040u   // fp32 [60]
#define WFT_    581100u

// ws float offsets (total 9,105,901 fl = 36.4 MB; ws >= 40 MB measured)
#define XG_O   0u         // [4 layers][2 ring][1024][720] fp32 = 5,898,240
#define HR_O   5898240u   // [3 layers][2 ring][1024][180] fp32 = 1,105,920
#define H3_O   7004160u   // bf16 [16384][180] = 1,474,560 fl
#define WFU_O  8478720u   // 581,100 fl
#define STH_O  9059820u   // [4][32][180]
#define STC_O  9082860u
#define FLAG_O 9105900u
#define XGSLOT 737280
#define HRSLOT 184320

#if defined(__has_builtin)
#if __has_builtin(__builtin_amdgcn_fdot2)
#define HAVE_FDOT2 1
#endif
#endif

typedef _Float16 f16x2 __attribute__((ext_vector_type(2)));

struct Plan {
  int nl; int ll[4]; int lc[4];
  int ng; int gl[4]; int gc[4];
};

__device__ __forceinline__ float sigf(float x)   { return 1.f / (1.f + __expf(-x)); }
__device__ __forceinline__ float tanhf2(float x) { return 2.f / (1.f + __expf(-2.f * x)) - 1.f; }
__device__ __forceinline__ float toF(__hip_bfloat16 x) { return __bfloat162float(x); }
__device__ __forceinline__ float ldr(const void* p, long i, int fl) {
  return fl ? ((const float*)p)[i] : toF(((const __hip_bfloat16*)p)[i]);
}
__device__ __forceinline__ unsigned f16b(_Float16 h) {
  union { _Float16 f; unsigned short s; } x; x.f = h; return x.s;
}
__device__ __forceinline__ float h2f(unsigned s) {
  union { unsigned short s; _Float16 f; } x; x.s = (unsigned short)(s & 0xFFFFu);
  return (float)x.f;
}
__device__ __forceinline__ f16x2 u2h(unsigned u) {
  union { unsigned u; f16x2 v; } x; x.u = u; return x.v;
}
__device__ __forceinline__ float fd2(unsigned hu, unsigned wu, float acc) {
#ifdef HAVE_FDOT2
  return __builtin_amdgcn_fdot2(u2h(hu), u2h(wu), acc, false);
#else
  return acc + h2f(hu) * h2f(wu) + h2f(hu >> 16) * h2f(wu >> 16);
#endif
}
__device__ __forceinline__ unsigned packpair_f32(float lo, float hi) {
  return f16b((_Float16)lo) | (f16b((_Float16)hi) << 16);
}
__device__ __forceinline__ unsigned packpair_bf16(unsigned u) {
  union { unsigned v; float f; } a, b;
  a.v = u << 16; b.v = u & 0xFFFF0000u;
  return packpair_f32(a.f, b.f);
}

// 23 groups x 4 Whh pair-words = 92 named scalars (SROA-proof, asm-pinned)
#define REP23(M) M(0) M(1) M(2) M(3) M(4) M(5) M(6) M(7) M(8) M(9) M(10) \
  M(11) M(12) M(13) M(14) M(15) M(16) M(17) M(18) M(19) M(20) M(21) M(22)
#define LW(n) \
  unsigned w##n##a = wp0[(4*n+0)*G4_], w##n##b = wp0[(4*n+1)*G4_], \
           w##n##c = wp0[(4*n+2)*G4_], w##n##d = wp0[(4*n+3)*G4_];
#define PW(n) \
  asm volatile("" : "+v"(w##n##a), "+v"(w##n##b), "+v"(w##n##c), "+v"(w##n##d));
#define ST(n) { \
  const uint4 hh = *(const uint4*)&hpk[4*n]; \
  a0 = fd2(hh.x, w##n##a, a0); a1 = fd2(hh.y, w##n##b, a1); \
  a2 = fd2(hh.z, w##n##c, a2); a3 = fd2(hh.w, w##n##d, a3); }

// ---------------------------------------------------------------------------
__global__ __launch_bounds__(256) void detect_kernel(
    const unsigned short* __restrict__ xw, int* __restrict__ flag) {
  __shared__ int cnt;
  if (threadIdx.x == 0) cnt = 0;
  __syncthreads();
  int lc = 0;
  for (int i = threadIdx.x; i < 2048; i += 256) {
    const int e = (xw[i] >> 7) & 0xFF;
    if (e >= 0xC0 || (e > 0 && e < 0x40)) lc++;
  }
  atomicAdd(&cnt, lc);
  __syncthreads();
  if (threadIdx.x == 0) *flag = (cnt > 100) ? 1 : 0;
}

// ---------------------------------------------------------------------------
// prep: Whh packed [l][jp][o]; Wih0 packed [o][150]; WihR packed [l][o][90];
// bias/linw/linb fp32.
// ---------------------------------------------------------------------------
__global__ __launch_bounds__(256) void prep_kernel(
    const void* __restrict__ wih0, const void* __restrict__ wihr,
    const void* __restrict__ whh,  const void* __restrict__ bih,
    const void* __restrict__ bhh,  const void* __restrict__ linw,
    const void* __restrict__ linb, float* __restrict__ wf,
    const int* __restrict__ flag) {
  const unsigned i = blockIdx.x * 256u + threadIdx.x;
  if (i >= WFT_) return;
  const int fl = *flag;
  if (i < PW0_O) {            // Whh packed transposed
    const unsigned l = i / 66240u, r = i % 66240u;
    const unsigned jp = r / 720u, o = r % 720u;
    unsigned u = 0u;
    if (jp < 90u) {
      const long b = (long)l * 129600 + (long)o * H_;
      u = packpair_f32(ldr(whh, b + 2 * jp, fl), ldr(whh, b + 2 * jp + 1, fl));
    }
    ((unsigned*)wf)[i] = u;
    return;
  }
  if (i < PWR_O) {            // Wih0 [o][150] pairs
    const unsigned j = i - PW0_O, o = j / 150u, kp = j % 150u;
    const long b = (long)o * IN_;
    ((unsigned*)wf)[i] =
        packpair_f32(ldr(wih0, b + 2 * kp, fl), ldr(wih0, b + 2 * kp + 1, fl));
    return;
  }
  if (i < BIASF_O) {          // WihR [l][o][90] pairs
    const unsigned j = i - PWR_O, l = j / 64800u, r = j % 64800u;
    const unsigned o = r / 90u, kp = r % 90u;
    const long b = (long)l * 129600 + (long)o * H_;
    ((unsigned*)wf)[i] =
        packpair_f32(ldr(wihr, b + 2 * kp, fl), ldr(wihr, b + 2 * kp + 1, fl));
    return;
  }
  float v;
  if (i < LINWF_O)      { const unsigned j = i - BIASF_O; v = ldr(bih, j, fl) + ldr(bhh, j, fl); }
  else if (i < LINBF_O) v = ldr(linw, i - LINWF_O, fl);
  else                  v = ldr(linb, i - LINBF_O, fl);
  wf[i] = v;
}

// ---------------------------------------------------------------------------
// fused: FIXED grid 512, co-residency mapping. LSTM slots at bids
// [0,64) u [256,320): under canonical placement (XCD = bid%8, round-robin
// within XCD) bids i and i+256 land on the SAME CU -> two LSTM blocks
// co-resident (24 waves) interleave their L2 weight-fetch waits. GEMM at
// [64,256) u [320,512). Bodies are the proven r0/r6 ones, unchanged.
// ---------------------------------------------------------------------------
__global__ __launch_bounds__(768, 3) void fused_kernel(
    const void* __restrict__ x, const int* __restrict__ flag,
    const unsigned* __restrict__ wfu,
    float* __restrict__ xg, float* __restrict__ hr,
    __hip_bfloat16* __restrict__ h3,
    float* __restrict__ sth, float* __restrict__ stc, Plan p) {
  __shared__ __align__(16) unsigned hpk[NPK_];
  __shared__ float gbuf[G4_];
  __shared__ __align__(16) unsigned Asu[3][10][68];
  __shared__ __align__(16) unsigned Bsu[3][10][68];

  const int bid = blockIdx.x;
  int lslot = -1;
  if (bid < 64) lslot = bid;
  else if (bid >= 256 && bid < 320) lslot = 64 + (bid - 256);

  if (lslot >= 0) {
    if (lslot >= p.nl * 32) return;     // uniform early exit, pre-barrier
    // ---------------- LSTM (r0 proven body, raw in-loop barriers) ----------
    const int j = lslot >> 5, b = lslot & 31;
    const int l = p.ll[j], c = p.lc[j];
    const int o = threadIdx.x;
    const bool act = o < G4_;
    const int oc = act ? o : 0;
    const unsigned* wp0 = wfu + PWHH_O + (unsigned)l * (NPK_ * G4_) + oc;
    REP23(LW)
    REP23(PW)
    const float* xgs = xg + (long)(l * 2 + (c & 1)) * XGSLOT;
    float* hrs = hr + (long)((l < 3 ? l : 0) * 2 + (c & 1)) * HRSLOT;
    float cst = 0.f;
    if (o == 180 || o == 181) hpk[o - 90] = 0u;
    if (o < H_) {
      float h = 0.f;
      if (c != 0) { h = sth[(l * 32 + b) * H_ + o]; cst = stc[(l * 32 + b) * H_ + o]; }
      const unsigned v = f16b((_Float16)h);
      const unsigned nx = __shfl_down(v, 1);
      if ((o & 1) == 0) hpk[o >> 1] = v | (nx << 16);
    }
    const float* xgp = xgs + (long)b * TC_ * G4_ + oc;
    float xcur = xgp[0];
    __syncthreads();
    for (int tl = 0; tl < TC_; ++tl) {
      {
        float a0 = xcur, a1 = 0.f, a2 = 0.f, a3 = 0.f;
        REP23(ST)
        const float acc = (a0 + a1) + (a2 + a3);
        const bool isg = (o >= 2 * H_) && (o < 3 * H_);
        if (act) gbuf[o] = isg ? tanhf2(acc) : sigf(acc);
        const int tn = (tl + 1 < TC_) ? tl + 1 : tl;
        xcur = xgp[(long)tn * G4_];
      }
      // raw barrier: gbuf (LDS) visible; global stores/prefetch not drained
      asm volatile("s_waitcnt lgkmcnt(0)\n\ts_barrier" ::: "memory");
      if (o < H_) {
        cst = gbuf[H_ + o] * cst + gbuf[o] * gbuf[2 * H_ + o];
        const float h = gbuf[3 * H_ + o] * tanhf2(cst);
        if (l < 3) hrs[(b * TC_ + tl) * H_ + o] = h;
        else h3[((long)b * S_ + c * TC_ + tl) * H_ + o] = __float2bfloat16(h);
        const unsigned v = f16b((_Float16)h);
        const unsigned nx = __shfl_down(v, 1);
        if ((o & 1) == 0) hpk[o >> 1] = v | (nx << 16);
        if (tl == TC_ - 1) {
          sth[(l * 32 + b) * H_ + o] = h; stc[(l * 32 + b) * H_ + o] = cst;
        }
      }
      // raw barrier: hpk (LDS) visible for next step's ST reads
      asm volatile("s_waitcnt lgkmcnt(0)\n\ts_barrier" ::: "memory");
    }
    return;
  }

  // ---------------- GEMM: f16-pair dot2, proven barrier tiling ----------
  const int gslot = (bid < 256) ? (bid - 64) : (bid - 320 + 192);
  if (gslot >= p.ng * 64) return;       // uniform early exit, pre-barrier
  const int g = threadIdx.x >> 8, t = threadIdx.x & 255;
  const int ti = gslot * 3 + g;         // ti < ng*192
  const int jj = ti / 192, idx = ti % 192;
  const int rt = idx & 15, ct = idx >> 4;
  const int l = p.gl[jj], c = p.gc[jj];
  const int fl = *flag;
  const int KP = (l == 0) ? 150 : 90;   // k-pairs
  const unsigned* Wp = (l == 0) ? (wfu + PW0_O)
                                : (wfu + PWR_O + (unsigned)(l - 1) * 64800u);
  const float* bias = (const float*)wfu + BIASF_O + (unsigned)l * G4_;
  const float* hA = (l == 0) ? nullptr
                  : hr + (long)((l - 1) * 2 + (c & 1)) * HRSLOT;
  float* dst = xg + (long)(l * 2 + (c & 1)) * XGSLOT;
  const int rho0 = rt * 64, o0 = ct * 64;
  const int tx = t & 15, ty = t >> 4;
  float acc[4][4] = {};
  for (int kp0 = 0; kp0 < KP; kp0 += 10) {
    for (int e = t; e < 640; e += 256) {
      const int rl = e / 10, pp = e % 10;
      const int rho = rho0 + rl;
      unsigned av;
      if (l == 0) {
        const int bb = rho >> 5, tl = rho & 31;
        const long gr = (long)bb * S_ + c * TC_ + tl;
        if (fl == 0) av = packpair_bf16(((const unsigned*)x)[gr * 150 + kp0 + pp]);
        else { const float2 f = ((const float2*)x)[gr * 150 + kp0 + pp];
               av = packpair_f32(f.x, f.y); }
      } else {
        const float2 f = ((const float2*)hA)[(long)rho * 90 + kp0 + pp];
        av = packpair_f32(f.x, f.y);
      }
      Asu[g][pp][rl] = av;
      const int o = o0 + rl;
      Bsu[g][pp][rl] = (o < G4_) ? Wp[(long)o * KP + kp0 + pp] : 0u;
    }
    __syncthreads();
#pragma unroll
    for (int pp = 0; pp < 10; ++pp) {
      const uint4 a4 = *(const uint4*)&Asu[g][pp][ty * 4];
      const uint4 b4 = *(const uint4*)&Bsu[g][pp][tx * 4];
      const unsigned av[4] = {a4.x, a4.y, a4.z, a4.w};
      const unsigned bv[4] = {b4.x, b4.y, b4.z, b4.w};
#pragma unroll
      for (int i = 0; i < 4; ++i)
#pragma unroll
        for (int j2 = 0; j2 < 4; ++j2) acc[i][j2] = fd2(av[i], bv[j2], acc[i][j2]);
    }
    __syncthreads();
  }
#pragma unroll
  for (int i = 0; i < 4; ++i) {
    const int rho = rho0 + ty * 4 + i;
#pragma unroll
    for (int j2 = 0; j2 < 4; ++j2) {
      const int o = o0 + tx * 4 + j2;
      if (o < G4_) dst[(long)rho * G4_ + o] = acc[i][j2] + bias[o];
    }
  }
}

// ---------------------------------------------------------------------------
// linear as tiled GEMM: [16384 x 180] @ [180 x 60] -> out[b][c][s].
// ---------------------------------------------------------------------------
__global__ __launch_bounds__(256) void linear_kernel(
    const __hip_bfloat16* __restrict__ h, const float* __restrict__ linw,
    const float* __restrict__ linb, float* __restrict__ out) {
  __shared__ __align__(16) float Ast[20][68];
  __shared__ __align__(16) float Bst[20][68];
  const int bt = blockIdx.x;
  const int b = bt >> 3, st0 = (bt & 7) * 64;
  const int t = threadIdx.x, tx = t & 15, ty = t >> 4;
  float acc[4][4] = {};
  for (int k0 = 0; k0 < H_; k0 += 20) {
    for (int e = t; e < 1280; e += 256) {
      const int rl = e / 20, kk = e % 20;
      Ast[kk][rl] = toF(h[(long)(b * S_ + st0 + rl) * H_ + k0 + kk]);
      Bst[kk][rl] = (rl < OUT_) ? linw[rl * H_ + k0 + kk] : 0.f;
    }
    __syncthreads();
#pragma unroll
    for (int kk = 0; kk < 20; ++kk) {
      const float4 a4 = *(const float4*)&Ast[kk][ty * 4];
      const float4 b4 = *(const float4*)&Bst[kk][tx * 4];
      const float av[4] = {a4.x, a4.y, a4.z, a4.w};
      const float bv[4] = {b4.x, b4.y, b4.z, b4.w};
#pragma unroll
      for (int i = 0; i < 4; ++i)
#pragma unroll
        for (int j2 = 0; j2 < 4; ++j2) acc[i][j2] += av[i] * bv[j2];
    }
    __syncthreads();
  }
#pragma unroll
  for (int i = 0; i < 4; ++i) {
    const int s = st0 + ty * 4 + i;
#pragma unroll
    for (int j2 = 0; j2 < 4; ++j2) {
      const int c = tx * 4 + j2;
      if (c < OUT_) out[((long)b * OUT_ + c) * S_ + s] = acc[i][j2] + linb[c];
    }
  }
}

// ---------------------------------------------------------------------------
__global__ __launch_bounds__(256) void mel_kernel(
    const float* __restrict__ in, float* __restrict__ out,
    const void* __restrict__ mw, const void* __restrict__ mb,
    int l, const int* __restrict__ flag) {
  const int fl = *flag;
  const int idx = blockIdx.x;
  const int s = (idx & 1) * 256 + threadIdx.x;
  const int c = (idx >> 1) % OUT_;
  const int b = idx / (2 * OUT_);
  const int j = c % 3, i = c / 3;
  float acc = ldr(mb, (l * 3 + j) * 20 + i, fl);
  const long wbase = (long)((l * 3 + j) * 20 + i) * 15;
#pragma unroll
  for (int q = 0; q < 3; ++q) {
    const int ch = 3 * i + q + j - 1;
    if (ch < 0 || ch >= OUT_) continue;
    const float* xr = in + ((long)b * OUT_ + ch) * S_;
#pragma unroll
    for (int k = 0; k < 5; ++k) {
      const int sp = s + k - 2;
      if (sp < 0 || sp >= S_) continue;
      acc += ldr(mw, wbase + q * 5 + k, fl) * xr[sp];
    }
  }
  out[((long)b * OUT_ + c) * S_ + s] = acc + in[((long)b * OUT_ + c) * S_ + s];
}

// ---------------------------------------------------------------------------
__global__ __launch_bounds__(256) void res_kernel(
    const float* __restrict__ lin, const float* __restrict__ mel,
    const void* __restrict__ rw, const void* __restrict__ rb,
    void* __restrict__ outp, const int* __restrict__ flag) {
  const int fl = *flag;
  const int q = threadIdx.x >> 6, lane = threadIdx.x & 63;
  const int bs = blockIdx.x * 4 + q;
  const int b = bs / S_, s = bs % S_;
  if (lane >= OUT_) return;
  const int c = lane;
  float acc = ldr(rb, c, fl);
  const float* x0 = lin + ((long)b * OUT_ + c) * S_;
  const float* x1 = mel + ((long)b * OUT_ + c) * S_;
#pragma unroll
  for (int k = 0; k < 5; ++k) {
    const int sp = s + k - 2;
    if (sp < 0 || sp >= S_) continue;
    acc += ldr(rw, c * 10 + k, fl) * x0[sp] + ldr(rw, c * 10 + 5 + k, fl) * x1[sp];
  }
  const long oi = (long)bs * OUT_ + c;
  if (fl == 0) ((__hip_bfloat16*)outp)[oi] = __float2bfloat16(acc);
  else ((float*)outp)[oi] = acc;
}

// ---------------------------------------------------------------------------
extern "C" void kernel_launch(void* const* d_in, const int* in_sizes, int n_in,
                              void* d_out, int out_size, void* d_ws, size_t ws_size,
                              hipStream_t stream) {
  const void* x    = d_in[0];
  const void* wih0 = d_in[1];
  const void* wihr = d_in[2];
  const void* whh  = d_in[3];
  const void* bih  = d_in[4];
  const void* bhh  = d_in[5];
  const void* linw = d_in[6];
  const void* linb = d_in[7];
  const void* melw = d_in[8];
  const void* melb = d_in[9];
  const void* resw = d_in[10];
  const void* resb = d_in[11];

  float* ws = (float*)d_ws;
  float* xg = ws + XG_O;
  float* hrp = ws + HR_O;
  __hip_bfloat16* h3 = (__hip_bfloat16*)(ws + H3_O);
  float* wf = ws + WFU_O;
  const unsigned* wfu = (const unsigned*)wf;
  float* sth = ws + STH_O;
  float* stc = ws + STC_O;
  int* flag = (int*)(ws + FLAG_O);
  float* lin = ws + XG_O;            // epilogue aliases dead xg region
  float* m1 = lin + 983040;
  float* m2 = m1 + 983040;

  detect_kernel<<<1, 256, 0, stream>>>((const unsigned short*)x, flag);
  prep_kernel<<<(WFT_ + 255) / 256, 256, 0, stream>>>(
      wih0, wihr, whh, bih, bhh, linw, linb, wf, flag);

  // prologue: gemm(0,0) only (fixed 512 grid, co-residency mapping)
  {
    Plan p = {};
    p.nl = 0; p.ng = 1; p.gl[0] = 0; p.gc[0] = 0;
    fused_kernel<<<512, 768, 0, stream>>>(x, flag, wfu, xg, hrp, h3, sth, stc, p);
  }
  // pipeline: lstm(l,c) at launch n = c + 2l; gemm(l,c) at n = c + 2l - 1
  for (int n = 0; n <= 21; ++n) {
    Plan p = {};
    for (int l = 0; l < 4; ++l) {
      const int c = n - 2 * l;
      if (c >= 0 && c < NC_) { p.ll[p.nl] = l; p.lc[p.nl] = c; p.nl++; }
    }
    for (int l = 0; l < 4; ++l) {
      const int c = n + 1 - 2 * l;
      if (c >= 0 && c < NC_) { p.gl[p.ng] = l; p.gc[p.ng] = c; p.ng++; }
    }
    fused_kernel<<<512, 768, 0, stream>>>(x, flag, wfu, xg, hrp, h3, sth, stc, p);
  }

  linear_kernel<<<256, 256, 0, stream>>>(h3, wf + LINWF_O, wf + LINBF_O, lin);
  mel_kernel<<<B_ * OUT_ * 2, 256, 0, stream>>>(lin, m1, melw, melb, 0, flag);
  mel_kernel<<<B_ * OUT_ * 2, 256, 0, stream>>>(m1, m2, melw, melb, 1, flag);
  mel_kernel<<<B_ * OUT_ * 2, 256, 0, stream>>>(m2, m1, melw, melb, 2, flag);
  res_kernel<<<R_ / 4, 256, 0, stream>>>(lin, m1, resw, resb, d_out, flag);
}